// Round 2
// baseline (453.410 us; speedup 1.0000x reference)
//
#include <hip/hip_runtime.h>
#include <hip/hip_bf16.h>

#define BT 16384   // B*T = 32*512
#define DIM 768
#define NH 12
#define DFF 3072

typedef __attribute__((ext_vector_type(8))) short short8;
typedef __attribute__((ext_vector_type(4))) float floatx4;
typedef __attribute__((ext_vector_type(4))) unsigned short ushort4b;

using bf16 = __hip_bfloat16;

static __device__ __forceinline__ float b2f(bf16 v) { return __bfloat162float(v); }
static __device__ __forceinline__ bf16 f2b(float v) { return __float2bfloat16(v); }

// async global->LDS DMA, 16B per lane; LDS dest is wave-uniform base (HW adds lane*16)
static __device__ __forceinline__ void gload_lds16(const void* g, void* l) {
    __builtin_amdgcn_global_load_lds(
        (const __attribute__((address_space(1))) unsigned int*)g,
        (__attribute__((address_space(3))) unsigned int*)l, 16, 0, 0);
}

// ---- small pack: wqkv [256][768] (rows>=216 zero), wo_t [768][96] (k>=72 zero) ----
__global__ __launch_bounds__(256) void pack_small_kernel(
    const float* __restrict__ Wq, const float* __restrict__ Wk, const float* __restrict__ Wv,
    const float* __restrict__ Wo, bf16* __restrict__ wqkv, bf16* __restrict__ wo_t)
{
    int i = blockIdx.x * 256 + threadIdx.x;
    const int S0 = 256 * 768, S1 = 768 * 96;
    if (i < S0) {
        int c = i / 768, dd = i % 768;
        float v = 0.f;
        if (c < 216) {
            int sel = c / 72, cc = c % 72, h = cc / 6, e = cc % 6;
            const float* W = (sel == 0) ? Wq : (sel == 1) ? Wk : Wv;   // (H, D, E)
            v = W[((size_t)h * 768 + dd) * 6 + e];
        }
        wqkv[i] = f2b(v);
    } else if ((i -= S0) < S1) {
        int n = i / 96, r = i % 96;              // Wo is (72, 768): [r][n]
        wo_t[i] = f2b(r < 72 ? Wo[r * 768 + n] : 0.f);
    }
}

// ---- tiled transpose: in fp32 [R][C] -> out bf16 [C][R]; grid (C/32, R/32), 256 thr ----
__global__ __launch_bounds__(256) void transpose_kernel(
    const float* __restrict__ in, bf16* __restrict__ out, int R, int C)
{
    __shared__ float t[32][33];
    int c0 = blockIdx.x * 32, r0 = blockIdx.y * 32;
    int cx = threadIdx.x & 31, ry = threadIdx.x >> 5;   // ry 0..7
#pragma unroll
    for (int j = 0; j < 4; j++)
        t[ry + j * 8][cx] = in[(size_t)(r0 + ry + j * 8) * C + c0 + cx];
    __syncthreads();
    int rx = cx, cy = ry;
#pragma unroll
    for (int j = 0; j < 4; j++)
        out[(size_t)(c0 + cy + j * 8) * R + r0 + rx] = f2b(t[rx][cy + j * 8]);
}

// ---------------- LayerNorm: 192 threads, float4 loads, 8B packed bf16 stores ----------------
__global__ __launch_bounds__(192) void ln_kernel(
    const float* __restrict__ x, const float* __restrict__ g, const float* __restrict__ be,
    bf16* __restrict__ out)
{
    int row = blockIdx.x;
    int tid = threadIdx.x;
    const float4* xr = (const float4*)(x + (size_t)row * DIM);
    float4 v = xr[tid];
    float s = v.x + v.y + v.z + v.w;
    float s2 = v.x * v.x + v.y * v.y + v.z * v.z + v.w * v.w;
#pragma unroll
    for (int off = 32; off; off >>= 1) {
        s += __shfl_down(s, off);
        s2 += __shfl_down(s2, off);
    }
    __shared__ float red[6];
    int wv = tid >> 6, ln = tid & 63;
    if (ln == 0) { red[wv] = s; red[3 + wv] = s2; }
    __syncthreads();
    float ts = red[0] + red[1] + red[2];
    float ts2 = red[3] + red[4] + red[5];
    float mean = ts * (1.f / 768.f);
    float var = ts2 * (1.f / 768.f) - mean * mean;
    float rstd = rsqrtf(var + 1e-5f);
    int c = tid * 4;
    float o0 = (v.x - mean) * rstd * g[c + 0] + be[c + 0];
    float o1 = (v.y - mean) * rstd * g[c + 1] + be[c + 1];
    float o2 = (v.z - mean) * rstd * g[c + 2] + be[c + 2];
    float o3 = (v.w - mean) * rstd * g[c + 3] + be[c + 3];
    bf16 h0 = f2b(o0), h1 = f2b(o1), h2 = f2b(o2), h3 = f2b(o3);
    ushort4b pk;
    pk[0] = *(unsigned short*)&h0; pk[1] = *(unsigned short*)&h1;
    pk[2] = *(unsigned short*)&h2; pk[3] = *(unsigned short*)&h3;
    *(ushort4b*)(out + (size_t)row * DIM + c) = pk;
}

// ---------------- MFMA bf16 GEMM (128x128, m97-structure) for small-N / small-K GEMMs ----------
template <int NSLAB, bool RELU, bool BIAS, bool RES, bool BF16OUT>
__global__ __launch_bounds__(256) void gemm_kernel(
    const bf16* __restrict__ A, const bf16* __restrict__ Bt,
    const float* __restrict__ bias, const float* __restrict__ res,
    void* __restrict__ Cv, int M, int N, int K)
{
    constexpr int SMEM_BYTES = BF16OUT ? (128 * 136 * 2) : (NSLAB * 2 * 128 * 32 * 2);
    __shared__ __align__(16) char smem[SMEM_BYTES];
    bf16* lA = (bf16*)smem;                       // [NSLAB][128][32]
    bf16* lB = lA + NSLAB * 128 * 32;

    const int tid = threadIdx.x;
    const int bm = blockIdx.x * 128;
    const int bn = blockIdx.y * 128;
    const int wave = tid >> 6, lane = tid & 63;
    const int wm = (wave >> 1) * 64, wn = (wave & 1) * 64;
    const int quad = lane >> 4, l16 = lane & 15;
    const int lrow = lane >> 2;          // 0..15: row within 16-row DMA slab
    const int lkc = (lane & 3) * 8;      // 0,8,16,24: k offset within slab

    floatx4 acc[4][4] = {};

    for (int k0 = 0; k0 < K; k0 += NSLAB * 32) {
#pragma unroll
        for (int s = 0; s < NSLAB; s++) {
#pragma unroll
            for (int it = 0; it < 2; it++) {
                int r = wave * 32 + it * 16;
                gload_lds16(A + (size_t)(bm + r + lrow) * K + k0 + s * 32 + lkc,
                            lA + s * 4096 + r * 32);
                gload_lds16(Bt + (size_t)(bn + r + lrow) * K + k0 + s * 32 + lkc,
                            lB + s * 4096 + r * 32);
            }
        }
        __syncthreads();
#pragma unroll
        for (int s = 0; s < NSLAB; s++) {
            short8 af[4], bfr[4];
#pragma unroll
            for (int mt = 0; mt < 4; mt++)
                af[mt] = *(const short8*)(lA + s * 4096 + (wm + mt * 16 + l16) * 32 + quad * 8);
#pragma unroll
            for (int nt = 0; nt < 4; nt++)
                bfr[nt] = *(const short8*)(lB + s * 4096 + (wn + nt * 16 + l16) * 32 + quad * 8);
#pragma unroll
            for (int mt = 0; mt < 4; mt++)
#pragma unroll
                for (int nt = 0; nt < 4; nt++)
                    acc[mt][nt] = __builtin_amdgcn_mfma_f32_16x16x32_bf16(af[mt], bfr[nt], acc[mt][nt], 0, 0, 0);
        }
        __syncthreads();
    }

    if constexpr (BF16OUT) {
        bf16* ltile = (bf16*)smem;   // safe: loop ended with __syncthreads()
#pragma unroll
        for (int mt = 0; mt < 4; mt++) {
#pragma unroll
            for (int nt = 0; nt < 4; nt++) {
                int tc = wn + nt * 16 + l16;
#pragma unroll
                for (int r = 0; r < 4; r++) {
                    int tr = wm + mt * 16 + quad * 4 + r;
                    float v0 = acc[mt][nt][r];
                    if constexpr (BIAS) v0 += bias[bn + tc];
                    if constexpr (RELU) v0 = fmaxf(v0, 0.f);
                    ltile[tr * 136 + tc] = f2b(v0);
                }
            }
        }
        __syncthreads();
        bf16* C = (bf16*)Cv;
        int rr0 = tid >> 4, col8 = (tid & 15) * 8;
        int gc = bn + col8;
#pragma unroll
        for (int p = 0; p < 8; p++) {
            int rr = p * 16 + rr0;
            if (gc < N)
                *(short8*)(C + (size_t)(bm + rr) * N + gc) =
                    *(const short8*)(ltile + rr * 136 + col8);
        }
    } else {
        float* C = (float*)Cv;
#pragma unroll
        for (int mt = 0; mt < 4; mt++) {
#pragma unroll
            for (int nt = 0; nt < 4; nt++) {
                int gc = bn + wn + nt * 16 + l16;
                if (gc < N) {
#pragma unroll
                    for (int r = 0; r < 4; r++) {
                        int gr = bm + wm + mt * 16 + quad * 4 + r;
                        float v0 = acc[mt][nt][r];
                        if constexpr (BIAS) v0 += bias[gc];
                        if constexpr (RES) v0 += res[(size_t)gr * N + gc];
                        if constexpr (RELU) v0 = fmaxf(v0, 0.f);
                        C[(size_t)gr * N + gc] = v0;
                    }
                }
            }
        }
    }
}

// ============== 256x192 4-phase GEMM (full-grid tiles for N%192==0 shapes) ====================
// BM=256, BN=192, BK=64, 512 threads = 8 waves (4M x 2N), per-wave 64x96 (4x6 16x16 frags).
// LDS: 2 buffers x (A[256][64] + B[192][64]) bf16 = 112 KiB dynamic, 1 block/CU.
// LDS layout per matrix: subtiled [row/16][col32-half][16][32] bf16 with st_16x32 swizzle
// (byte-col ^= 32 when row&8). Staged via global_load_lds in 8KB chunks (1 load/thread/chunk),
// linear LDS dest + inverse-swizzled per-lane GLOBAL source; ds_read applies the same XOR.
// Phase order per K-tile group g (raw s_barrier pairs, NO vmcnt drain):
//   ph0: read A(qm0)+B(qn0);                MM(0,0)
//   ph1: read A(qm1);                       MM(1,0)   [A fully read after ph1]
//   ph2: read B(qn1); stage A0..A3(g+2);    MM(1,1)   [B fully read after ph2]
//   ph3: stage B0..B2(g+2);                 MM(0,1); vmcnt
// Every staged region's reads complete >=1 barrier before the stage issues (race-free).
// vmcnt(7) at group end drains exactly tile g+1 (7 chunks, issued a full group earlier -> free).
// Requires M%256==0, N%192==0, K%64==0, NT>=3, nwg%8==0.
template <bool RELU, bool BIAS, bool RES, bool BF16OUT>
__global__ __launch_bounds__(512, 2) void gemm192_kernel(
    const bf16* __restrict__ A, const bf16* __restrict__ Bt,
    const float* __restrict__ bias, const float* __restrict__ res,
    void* __restrict__ Cv, int M, int N, int K)
{
    extern __shared__ __align__(16) char smem[];
    const int NT = K >> 6;
    const int nbm = M >> 8;
    const int nwg = nbm * (N / 192);
    int idx = blockIdx.x;
    idx = (idx & 7) * (nwg >> 3) + (idx >> 3);      // XCD swizzle (nwg % 8 == 0)
    const int bm = (idx % nbm) << 8;
    const int bn = (idx / nbm) * 192;

    const int tid = threadIdx.x;
    const int w = tid >> 6, lane = tid & 63;
    const int wm = w >> 1, wn = w & 1;              // 4 x 2 wave grid
    const int l16 = lane & 15, quad = lane >> 4;

    // staging: chunk = 64 rows x 64 cols bf16 = 8KB, one gload_lds16 per thread.
    // DMA-linear byte (w*1024 + lane*16) lands at logical row (w>>1)*16+(lane>>2),
    // col-half (w&1), byte-col (lane&3)*16 of the subtiled layout -> inverse-swizzle the source.
    const int rstg = (w >> 1) * 16 + (lane >> 2);                       // 0..63 chunk-relative
    const int cstg = (w & 1) * 32 + (((lane & 3) * 8) ^ ((lane & 32) ? 16 : 0));   // elements
    const bf16* aSrc = A + (size_t)(bm + rstg) * K + cstg;
    const bf16* bSrc = Bt + (size_t)(bn + rstg) * K + cstg;
    const int stgoff = w * 1024;                    // wave-uniform; HW adds lane*16

    // swizzled ds_read: logical (row R, kslab s, quad) -> byte
    //   (R>>4)*2048 + s*1024 + (R&15)*64 + (quad*16 ^ ((R&8)?32:0));  R&15==l16, R&8==l16&8
    const int xr = (quad * 16) ^ ((l16 & 8) ? 32 : 0);
    const int aoff = wm * 8192 + l16 * 64 + xr;             // + qm*4096 + fm*2048 + s*1024
    const int boff = 32768 + wn * 12288 + l16 * 64 + xr;    // + qn*6144 + fn*2048 + s*1024

#define STG(BO, ISB, CH, T) gload_lds16( \
        ((ISB) ? bSrc : aSrc) + (size_t)(CH) * 64 * K + (size_t)(T) * 64, \
        smem + (BO) + (ISB) * 32768 + (CH) * 8192 + stgoff)

#define BARX() asm volatile("s_barrier" ::: "memory")
#define VMW(N_) asm volatile("s_waitcnt vmcnt(" #N_ ")" ::: "memory")

    floatx4 acc[4][6] = {};
    short8 a[2][2][2], b[3][2];                     // a[qm][fm][s], b[fn][s]

#define LDA(QM, CB) { _Pragma("unroll") for (int fm = 0; fm < 2; fm++) { \
    _Pragma("unroll") for (int s = 0; s < 2; s++) \
        a[QM][fm][s] = *(const short8*)((CB) + aoff + (QM) * 4096 + fm * 2048 + s * 1024); } }
#define LDB(QN, CB) { _Pragma("unroll") for (int fn = 0; fn < 3; fn++) { \
    _Pragma("unroll") for (int s = 0; s < 2; s++) \
        b[fn][s] = *(const short8*)((CB) + boff + (QN) * 6144 + fn * 2048 + s * 1024); } }
#define MM(QM, QN) { __builtin_amdgcn_s_setprio(1); \
    _Pragma("unroll") for (int fm = 0; fm < 2; fm++) { \
    _Pragma("unroll") for (int fn = 0; fn < 3; fn++) { \
    _Pragma("unroll") for (int s = 0; s < 2; s++) \
        acc[(QM)*2+fm][(QN)*3+fn] = __builtin_amdgcn_mfma_f32_16x16x32_bf16( \
            a[QM][fm][s], b[fn][s], acc[(QM)*2+fm][(QN)*3+fn], 0, 0, 0); } } \
    __builtin_amdgcn_s_setprio(0); }

    // prologue: all 7 chunks of tile0 -> buf0, tile1 -> buf1 (14 loads/thread)
#pragma unroll
    for (int c = 0; c < 4; c++) STG(0, 0, c, 0);
#pragma unroll
    for (int c = 0; c < 3; c++) STG(0, 1, c, 0);
#pragma unroll
    for (int c = 0; c < 4; c++) STG(57344, 0, c, 1);
#pragma unroll
    for (int c = 0; c < 3; c++) STG(57344, 1, c, 1);
    VMW(7);            // tile0's 7 chunks landed (tile1 stays in flight)
    BARX();

    for (int g = 0; g < NT; ++g) {
        const int bo = (g & 1) * 57344;
        const char* cb = smem + bo;
        // ---- phase 0: MM(0,0) ----
        LDA(0, cb); LDB(0, cb);
        BARX(); MM(0, 0); BARX();
        // ---- phase 1: MM(1,0) ----
        LDA(1, cb);
        BARX(); MM(1, 0); BARX();
        // ---- phase 2: MM(1,1); stage A chunks of tile g+2 (A reads done after ph1) ----
        LDB(1, cb);
        if (g + 2 < NT) { STG(bo, 0, 0, g + 2); STG(bo, 0, 1, g + 2);
                          STG(bo, 0, 2, g + 2); STG(bo, 0, 3, g + 2); }
        BARX(); MM(1, 1); BARX();
        // ---- phase 3: MM(0,1); stage B chunks (B reads done after ph2) ----
        if (g + 2 < NT) { STG(bo, 1, 0, g + 2); STG(bo, 1, 1, g + 2); STG(bo, 1, 2, g + 2); }
        BARX(); MM(0, 1);
        if (g < NT - 2) { VMW(7); } else { VMW(0); }
        BARX();
    }

    if constexpr (BF16OUT) {
        bf16* lt = (bf16*)smem;                     // all LDS traffic done (final barrier above)
#pragma unroll
        for (int mf = 0; mf < 4; mf++) {
            const int row = wm * 64 + mf * 16 + quad * 4;
#pragma unroll
            for (int nf = 0; nf < 6; nf++) {
                const int col = wn * 96 + nf * 16 + l16;
                float bv = BIAS ? bias[bn + col] : 0.f;
#pragma unroll
                for (int r = 0; r < 4; r++) {
                    float v = acc[mf][nf][r] + bv;
                    if constexpr (RELU) v = fmaxf(v, 0.f);
                    lt[(row + r) * 200 + col] = f2b(v);
                }
            }
        }
        __syncthreads();
        bf16* C = (bf16*)Cv;
#pragma unroll
        for (int it = 0; it < 12; it++) {
            int c = it * 512 + tid;                 // 256 rows x 24 chunks of 8
            int rr = c / 24, cc = (c - rr * 24) * 8;
            *(short8*)(C + (size_t)(bm + rr) * N + bn + cc) =
                *(const short8*)(lt + rr * 200 + cc);
        }
    } else {
        float* C = (float*)Cv;
#pragma unroll
        for (int mf = 0; mf < 4; mf++) {
            const int gr = bm + wm * 64 + mf * 16 + quad * 4;
#pragma unroll
            for (int nf = 0; nf < 6; nf++) {
                const int gc = bn + wn * 96 + nf * 16 + l16;
                float bv = BIAS ? bias[gc] : 0.f;
#pragma unroll
                for (int r = 0; r < 4; r++) {
                    float v = acc[mf][nf][r] + bv;
                    if constexpr (RES) v += res[(size_t)(gr + r) * N + gc];
                    if constexpr (RELU) v = fmaxf(v, 0.f);
                    C[(size_t)(gr + r) * N + gc] = v;
                }
            }
        }
    }
#undef STG
#undef BARX
#undef VMW
#undef LDA
#undef LDB
#undef MM
}

// ---------------- causal attention, online softmax; qkv layout [BT][216]: q|k|v each 72 cols ----------------
__global__ __launch_bounds__(256) void attn_kernel(const bf16* __restrict__ qkv, bf16* __restrict__ o_pad)
{
    int blk = blockIdx.x;
    int half = blk & 1;
    int bh = blk >> 1;
    int b = bh / NH, h = bh % NH;
    int wave = threadIdx.x >> 6, lane = threadIdx.x & 63;
    const int jmap0[4] = {0, 2, 5, 7}, jmap1[4] = {1, 3, 4, 6};
    int j = half ? jmap1[wave] : jmap0[wave];
    int t = j * 64 + lane;
    int smax = half ? 448 : 512;

    __shared__ float ks[512 * 6];
    __shared__ float vs[512 * 6];
    const bf16* base = qkv + (size_t)b * 512 * 216;
    for (int i = threadIdx.x; i < smax * 6; i += 256) {
        int s = i / 6, e = i % 6;
        ks[i] = b2f(base[s * 216 + 72 + h * 6 + e]);
        vs[i] = b2f(base[s * 216 + 144 + h * 6 + e]);
    }
    __syncthreads();

    float q0 = b2f(base[t * 216 + h * 6 + 0]);
    float q1 = b2f(base[t * 216 + h * 6 + 1]);
    float q2 = b2f(base[t * 216 + h * 6 + 2]);
    float q3 = b2f(base[t * 216 + h * 6 + 3]);
    float q4 = b2f(base[t * 216 + h * 6 + 4]);
    float q5 = b2f(base[t * 216 + h * 6 + 5]);

    const float scale = 0.4082482904638630f;  // 1/sqrt(6)
    float m = -1e30f, l = 0.f;
    float o0 = 0, o1 = 0, o2 = 0, o3 = 0, o4 = 0, o5 = 0;
    for (int s = 0; s <= t; s++) {
        const float* kk = &ks[s * 6];
        float sc = (q0 * kk[0] + q1 * kk[1] + q2 * kk[2] + q3 * kk[3] + q4 * kk[4] + q5 * kk[5]) * scale;
        float nm = fmaxf(m, sc);
        float alpha = __expf(m - nm);
        float p = __expf(sc - nm);
        l = l * alpha + p;
        const float* vv = &vs[s * 6];
        o0 = o0 * alpha + p * vv[0];
        o1 = o1 * alpha + p * vv[1];
        o2 = o2 * alpha + p * vv[2];
        o3 = o3 * alpha + p * vv[3];
        o4 = o4 * alpha + p * vv[4];
        o5 = o5 * alpha + p * vv[5];
        m = nm;
    }
    float inv = 1.f / l;
    bf16* orow = o_pad + (size_t)(b * 512 + t) * 96 + h * 6;
    orow[0] = f2b(o0 * inv);
    orow[1] = f2b(o1 * inv);
    orow[2] = f2b(o2 * inv);
    orow[3] = f2b(o3 * inv);
    orow[4] = f2b(o4 * inv);
    orow[5] = f2b(o5 * inv);
    // cols 72..95 of o_pad stay poison (finite bf16): matching wo_t k-cols are zero -> contributes 0.
}

extern "C" void kernel_launch(void* const* d_in, const int* in_sizes, int n_in,
                              void* d_out, int out_size, void* d_ws, size_t ws_size,
                              hipStream_t stream)
{
    const float* x   = (const float*)d_in[0];
    const float* Wq  = (const float*)d_in[1];
    const float* Wk  = (const float*)d_in[2];
    const float* Wv  = (const float*)d_in[3];
    const float* Wo  = (const float*)d_in[4];
    const float* bo  = (const float*)d_in[5];
    const float* W1  = (const float*)d_in[6];
    const float* b1  = (const float*)d_in[7];
    const float* W2  = (const float*)d_in[8];
    const float* b2  = (const float*)d_in[9];
    const float* g1  = (const float*)d_in[10];
    const float* be1 = (const float*)d_in[11];
    const float* g2  = (const float*)d_in[12];
    const float* be2 = (const float*)d_in[13];

    char* ws = (char*)d_ws;
    size_t off = 0;
    auto alloc = [&](size_t bytes) {
        void* p = ws + off;
        off = (off + bytes + 255) & ~(size_t)255;
        return p;
    };
    bf16*  xn    = (bf16*)alloc((size_t)BT * DIM * 2);   // LN output (reused for both LNs)
    bf16*  qkvb  = (bf16*)alloc((size_t)BT * 216 * 2);
    bf16*  o_pad = (bf16*)alloc((size_t)BT * 96 * 2);
    float* x1    = (float*)alloc((size_t)BT * DIM * 4);  // residual stream after attention, fp32
    bf16*  ffb   = (bf16*)alloc((size_t)BT * DFF * 2);
    bf16*  wqkv  = (bf16*)alloc((size_t)256 * 768 * 2);  // padded to 256 rows (zeros)
    bf16*  wo_t  = (bf16*)alloc((size_t)768 * 96 * 2);
    bf16*  w1t   = (bf16*)alloc((size_t)3072 * 768 * 2);
    bf16*  w2t   = (bf16*)alloc((size_t)768 * 3072 * 2);

    // allow >64KB dynamic LDS on the 256x192 kernels (host-side, graph-capture safe)
    hipFuncSetAttribute(reinterpret_cast<const void*>(&gemm192_kernel<true, true, false, true>),
                        hipFuncAttributeMaxDynamicSharedMemorySize, 114688);
    hipFuncSetAttribute(reinterpret_cast<const void*>(&gemm192_kernel<false, true, true, false>),
                        hipFuncAttributeMaxDynamicSharedMemorySize, 114688);

    const int PACK_N = 256 * 768 + 768 * 96;
    pack_small_kernel<<<(PACK_N + 255) / 256, 256, 0, stream>>>(Wq, Wk, Wv, Wo, wqkv, wo_t);
    transpose_kernel<<<dim3(3072 / 32, 768 / 32), 256, 0, stream>>>(W1, w1t, 768, 3072);
    transpose_kernel<<<dim3(768 / 32, 3072 / 32), 256, 0, stream>>>(W2, w2t, 3072, 768);

    ln_kernel<<<BT, 192, 0, stream>>>(x, g1, be1, xn);
    gemm_kernel<2, false, false, false, true><<<dim3(128, 2), 256, 0, stream>>>(
        xn, wqkv, nullptr, nullptr, qkvb, BT, 216, 768);
    attn_kernel<<<32 * NH * 2, 256, 0, stream>>>(qkvb, o_pad);
    gemm_kernel<1, false, true, true, false><<<dim3(128, 6), 256, 0, stream>>>(
        o_pad, wo_t, bo, x, x1, BT, 768, 96);
    ln_kernel<<<BT, 192, 0, stream>>>(x1, g2, be2, xn);
    // FF1: [16384x768] @ [768x3072] -> bf16 (+bias, relu): grid 64x16 = 1024 (4 full rounds)
    gemm192_kernel<true, true, false, true><<<1024, 512, 114688, stream>>>(
        xn, w1t, b1, nullptr, ffb, BT, 3072, 768);
    // FF2: [16384x3072] @ [3072x768] -> fp32 (+bias, +res): grid 64x4 = 256 (full machine)
    gemm192_kernel<false, true, true, false><<<256, 512, 114688, stream>>>(
        ffb, w2t, b2, x1, (float*)d_out, BT, 768, 3072);
}

// Round 3
// 437.537 us; speedup vs baseline: 1.0363x; 1.0363x over previous
//
#include <hip/hip_runtime.h>
#include <hip/hip_bf16.h>

#define BT 16384   // B*T = 32*512
#define DIM 768
#define NH 12
#define DFF 3072

typedef __attribute__((ext_vector_type(8))) short short8;
typedef __attribute__((ext_vector_type(4))) float floatx4;
typedef __attribute__((ext_vector_type(4))) unsigned short ushort4b;

using bf16 = __hip_bfloat16;

static __device__ __forceinline__ float b2f(bf16 v) { return __bfloat162float(v); }
static __device__ __forceinline__ bf16 f2b(float v) { return __float2bfloat16(v); }

// async global->LDS DMA, 16B per lane; LDS dest is wave-uniform base (HW adds lane*16)
static __device__ __forceinline__ void gload_lds16(const void* g, void* l) {
    __builtin_amdgcn_global_load_lds(
        (const __attribute__((address_space(1))) unsigned int*)g,
        (__attribute__((address_space(3))) unsigned int*)l, 16, 0, 0);
}

// ---- small pack: wqkv [256][768] (rows>=216 zero), wo_t [768][96] (k>=72 zero) ----
__global__ __launch_bounds__(256) void pack_small_kernel(
    const float* __restrict__ Wq, const float* __restrict__ Wk, const float* __restrict__ Wv,
    const float* __restrict__ Wo, bf16* __restrict__ wqkv, bf16* __restrict__ wo_t)
{
    int i = blockIdx.x * 256 + threadIdx.x;
    const int S0 = 256 * 768, S1 = 768 * 96;
    if (i < S0) {
        int c = i / 768, dd = i % 768;
        float v = 0.f;
        if (c < 216) {
            int sel = c / 72, cc = c % 72, h = cc / 6, e = cc % 6;
            const float* W = (sel == 0) ? Wq : (sel == 1) ? Wk : Wv;   // (H, D, E)
            v = W[((size_t)h * 768 + dd) * 6 + e];
        }
        wqkv[i] = f2b(v);
    } else if ((i -= S0) < S1) {
        int n = i / 96, r = i % 96;              // Wo is (72, 768): [r][n]
        wo_t[i] = f2b(r < 72 ? Wo[r * 768 + n] : 0.f);
    }
}

// ---- tiled transpose: in fp32 [R][C] -> out bf16 [C][R]; grid (C/32, R/32), 256 thr ----
__global__ __launch_bounds__(256) void transpose_kernel(
    const float* __restrict__ in, bf16* __restrict__ out, int R, int C)
{
    __shared__ float t[32][33];
    int c0 = blockIdx.x * 32, r0 = blockIdx.y * 32;
    int cx = threadIdx.x & 31, ry = threadIdx.x >> 5;   // ry 0..7
#pragma unroll
    for (int j = 0; j < 4; j++)
        t[ry + j * 8][cx] = in[(size_t)(r0 + ry + j * 8) * C + c0 + cx];
    __syncthreads();
    int rx = cx, cy = ry;
#pragma unroll
    for (int j = 0; j < 4; j++)
        out[(size_t)(c0 + cy + j * 8) * R + r0 + rx] = f2b(t[rx][cy + j * 8]);
}

// ---------------- LayerNorm: 192 threads, float4 loads, 8B packed bf16 stores ----------------
__global__ __launch_bounds__(192) void ln_kernel(
    const float* __restrict__ x, const float* __restrict__ g, const float* __restrict__ be,
    bf16* __restrict__ out)
{
    int row = blockIdx.x;
    int tid = threadIdx.x;
    const float4* xr = (const float4*)(x + (size_t)row * DIM);
    float4 v = xr[tid];
    float s = v.x + v.y + v.z + v.w;
    float s2 = v.x * v.x + v.y * v.y + v.z * v.z + v.w * v.w;
#pragma unroll
    for (int off = 32; off; off >>= 1) {
        s += __shfl_down(s, off);
        s2 += __shfl_down(s2, off);
    }
    __shared__ float red[6];
    int wv = tid >> 6, ln = tid & 63;
    if (ln == 0) { red[wv] = s; red[3 + wv] = s2; }
    __syncthreads();
    float ts = red[0] + red[1] + red[2];
    float ts2 = red[3] + red[4] + red[5];
    float mean = ts * (1.f / 768.f);
    float var = ts2 * (1.f / 768.f) - mean * mean;
    float rstd = rsqrtf(var + 1e-5f);
    int c = tid * 4;
    float o0 = (v.x - mean) * rstd * g[c + 0] + be[c + 0];
    float o1 = (v.y - mean) * rstd * g[c + 1] + be[c + 1];
    float o2 = (v.z - mean) * rstd * g[c + 2] + be[c + 2];
    float o3 = (v.w - mean) * rstd * g[c + 3] + be[c + 3];
    bf16 h0 = f2b(o0), h1 = f2b(o1), h2 = f2b(o2), h3 = f2b(o3);
    ushort4b pk;
    pk[0] = *(unsigned short*)&h0; pk[1] = *(unsigned short*)&h1;
    pk[2] = *(unsigned short*)&h2; pk[3] = *(unsigned short*)&h3;
    *(ushort4b*)(out + (size_t)row * DIM + c) = pk;
}

// ---------------- MFMA bf16 GEMM (128x128, m97-structure) for small-N / small-K GEMMs ----------
template <int NSLAB, bool RELU, bool BIAS, bool RES, bool BF16OUT>
__global__ __launch_bounds__(256) void gemm_kernel(
    const bf16* __restrict__ A, const bf16* __restrict__ Bt,
    const float* __restrict__ bias, const float* __restrict__ res,
    void* __restrict__ Cv, int M, int N, int K)
{
    constexpr int SMEM_BYTES = BF16OUT ? (128 * 136 * 2) : (NSLAB * 2 * 128 * 32 * 2);
    __shared__ __align__(16) char smem[SMEM_BYTES];
    bf16* lA = (bf16*)smem;                       // [NSLAB][128][32]
    bf16* lB = lA + NSLAB * 128 * 32;

    const int tid = threadIdx.x;
    const int bm = blockIdx.x * 128;
    const int bn = blockIdx.y * 128;
    const int wave = tid >> 6, lane = tid & 63;
    const int wm = (wave >> 1) * 64, wn = (wave & 1) * 64;
    const int quad = lane >> 4, l16 = lane & 15;
    const int lrow = lane >> 2;          // 0..15: row within 16-row DMA slab
    const int lkc = (lane & 3) * 8;      // 0,8,16,24: k offset within slab

    floatx4 acc[4][4] = {};

    for (int k0 = 0; k0 < K; k0 += NSLAB * 32) {
#pragma unroll
        for (int s = 0; s < NSLAB; s++) {
#pragma unroll
            for (int it = 0; it < 2; it++) {
                int r = wave * 32 + it * 16;
                gload_lds16(A + (size_t)(bm + r + lrow) * K + k0 + s * 32 + lkc,
                            lA + s * 4096 + r * 32);
                gload_lds16(Bt + (size_t)(bn + r + lrow) * K + k0 + s * 32 + lkc,
                            lB + s * 4096 + r * 32);
            }
        }
        __syncthreads();
#pragma unroll
        for (int s = 0; s < NSLAB; s++) {
            short8 af[4], bfr[4];
#pragma unroll
            for (int mt = 0; mt < 4; mt++)
                af[mt] = *(const short8*)(lA + s * 4096 + (wm + mt * 16 + l16) * 32 + quad * 8);
#pragma unroll
            for (int nt = 0; nt < 4; nt++)
                bfr[nt] = *(const short8*)(lB + s * 4096 + (wn + nt * 16 + l16) * 32 + quad * 8);
#pragma unroll
            for (int mt = 0; mt < 4; mt++)
#pragma unroll
                for (int nt = 0; nt < 4; nt++)
                    acc[mt][nt] = __builtin_amdgcn_mfma_f32_16x16x32_bf16(af[mt], bfr[nt], acc[mt][nt], 0, 0, 0);
        }
        __syncthreads();
    }

    if constexpr (BF16OUT) {
        bf16* ltile = (bf16*)smem;   // safe: loop ended with __syncthreads()
#pragma unroll
        for (int mt = 0; mt < 4; mt++) {
#pragma unroll
            for (int nt = 0; nt < 4; nt++) {
                int tc = wn + nt * 16 + l16;
#pragma unroll
                for (int r = 0; r < 4; r++) {
                    int tr = wm + mt * 16 + quad * 4 + r;
                    float v0 = acc[mt][nt][r];
                    if constexpr (BIAS) v0 += bias[bn + tc];
                    if constexpr (RELU) v0 = fmaxf(v0, 0.f);
                    ltile[tr * 136 + tc] = f2b(v0);
                }
            }
        }
        __syncthreads();
        bf16* C = (bf16*)Cv;
        int rr0 = tid >> 4, col8 = (tid & 15) * 8;
        int gc = bn + col8;
#pragma unroll
        for (int p = 0; p < 8; p++) {
            int rr = p * 16 + rr0;
            if (gc < N)
                *(short8*)(C + (size_t)(bm + rr) * N + gc) =
                    *(const short8*)(ltile + rr * 136 + col8);
        }
    } else {
        float* C = (float*)Cv;
#pragma unroll
        for (int mt = 0; mt < 4; mt++) {
#pragma unroll
            for (int nt = 0; nt < 4; nt++) {
                int gc = bn + wn + nt * 16 + l16;
                if (gc < N) {
#pragma unroll
                    for (int r = 0; r < 4; r++) {
                        int gr = bm + wm + mt * 16 + quad * 4 + r;
                        float v0 = acc[mt][nt][r];
                        if constexpr (BIAS) v0 += bias[gc];
                        if constexpr (RES) v0 += res[(size_t)gr * N + gc];
                        if constexpr (RELU) v0 = fmaxf(v0, 0.f);
                        C[(size_t)gr * N + gc] = v0;
                    }
                }
            }
        }
    }
}

// ============== 256x192 4-phase GEMM with read-ahead-by-one-phase ============================
// BM=256, BN=192, BK=64, 512 threads = 8 waves (4M x 2N), per-wave 64x96 (4x6 16x16 frags).
// LDS: 2 buffers x (A[256][64] + B[192][64]) bf16 = 112 KiB dynamic, 1 block/CU.
// st_16x32 swizzled subtiled layout; staged via global_load_lds (linear dest + inverse-swizzled
// per-lane global source); ds_read applies the same XOR.
// Read-ahead schedule: every phase's MFMA operands were ds_read a full phase earlier, so their
// latency hides under the previous MFMA cluster. ONE barrier per phase (4/group):
//   ph0: issue A(qm1) reads;                         MM(0,0); BAR
//   ph1: issue B(qn1) reads;                         MM(1,0); BAR
//   ph2: issue A-stage(g+2, 4 chunks);               MM(1,1); VMW; BAR
//   ph3: pre-read B(qn0) of g+1; B-stage(g+2, 3);    MM(0,1); pre-read A(qm0) of g+1; BAR
// Race discipline (cross-wave, barrier-separated): each LDS region's reads are consumed (lgkm-
// drained before the consuming wave reaches the next barrier) >=1 barrier before that region is
// re-staged; pre-reads of buffer p^1 occur only after the VMW+BAR that publishes tile g+1.
// VMW(4) in ph2: outstanding = tile g+1's 7 chunks + tile g+2's 4 A-chunks -> drains tile g+1.
// Requires M%256==0, N%192==0, K%64==0, NT>=3, nwg%8==0.
template <bool RELU, bool BIAS, bool RES, bool BF16OUT>
__global__ __launch_bounds__(512, 2) void gemm192_kernel(
    const bf16* __restrict__ A, const bf16* __restrict__ Bt,
    const float* __restrict__ bias, const float* __restrict__ res,
    void* __restrict__ Cv, int M, int N, int K)
{
    extern __shared__ __align__(16) char smem[];
    const int NT = K >> 6;
    const int nbm = M >> 8;
    const int nwg = nbm * (N / 192);
    int idx = blockIdx.x;
    idx = (idx & 7) * (nwg >> 3) + (idx >> 3);      // XCD swizzle (nwg % 8 == 0)
    const int bm = (idx % nbm) << 8;
    const int bn = (idx / nbm) * 192;

    const int tid = threadIdx.x;
    const int w = tid >> 6, lane = tid & 63;
    const int wm = w >> 1, wn = w & 1;              // 4 x 2 wave grid
    const int l16 = lane & 15, quad = lane >> 4;

    // staging: chunk = 64 rows x 64 cols bf16 = 8KB, one gload_lds16 per thread.
    const int rstg = (w >> 1) * 16 + (lane >> 2);
    const int cstg = (w & 1) * 32 + (((lane & 3) * 8) ^ ((lane & 32) ? 16 : 0));
    const bf16* aSrc = A + (size_t)(bm + rstg) * K + cstg;
    const bf16* bSrc = Bt + (size_t)(bn + rstg) * K + cstg;
    const int stgoff = w * 1024;                    // wave-uniform; HW adds lane*16

    // swizzled ds_read: logical (row R, kslab s, quad) -> byte
    //   (R>>4)*2048 + s*1024 + (R&15)*64 + (quad*16 ^ ((R&8)?32:0))
    const int xr = (quad * 16) ^ ((l16 & 8) ? 32 : 0);
    const int aoff = wm * 8192 + l16 * 64 + xr;             // + qm*4096 + fm*2048 + s*1024
    const int boff = 32768 + wn * 12288 + l16 * 64 + xr;    // + qn*6144 + fn*2048 + s*1024

#define STG(BO, ISB, CH, T) gload_lds16( \
        ((ISB) ? bSrc : aSrc) + (size_t)(CH) * 64 * K + (size_t)(T) * 64, \
        smem + (BO) + (ISB) * 32768 + (CH) * 8192 + stgoff)

#define BARX() asm volatile("s_barrier" ::: "memory")
#define VMW(N_) asm volatile("s_waitcnt vmcnt(" #N_ ")" ::: "memory")

    floatx4 acc[4][6] = {};
    short8 a[2][2][2], b[2][3][2];                  // a[qm][fm][s], b[qn][fn][s]

#define LDA(QM, CB) { _Pragma("unroll") for (int fm = 0; fm < 2; fm++) { \
    _Pragma("unroll") for (int s = 0; s < 2; s++) \
        a[QM][fm][s] = *(const short8*)((CB) + aoff + (QM) * 4096 + fm * 2048 + s * 1024); } }
#define LDB(QN, CB) { _Pragma("unroll") for (int fn = 0; fn < 3; fn++) { \
    _Pragma("unroll") for (int s = 0; s < 2; s++) \
        b[QN][fn][s] = *(const short8*)((CB) + boff + (QN) * 6144 + fn * 2048 + s * 1024); } }
#define MM(QM, QN) { __builtin_amdgcn_s_setprio(1); \
    _Pragma("unroll") for (int fm = 0; fm < 2; fm++) { \
    _Pragma("unroll") for (int fn = 0; fn < 3; fn++) { \
    _Pragma("unroll") for (int s = 0; s < 2; s++) \
        acc[(QM)*2+fm][(QN)*3+fn] = __builtin_amdgcn_mfma_f32_16x16x32_bf16( \
            a[QM][fm][s], b[(QN)][fn][s], acc[(QM)*2+fm][(QN)*3+fn], 0, 0, 0); } } \
    __builtin_amdgcn_s_setprio(0); }

    // prologue: all 7 chunks of tile0 -> buf0, then tile1 -> buf1 (issue order matters for VMW)
#pragma unroll
    for (int c = 0; c < 4; c++) STG(0, 0, c, 0);
#pragma unroll
    for (int c = 0; c < 3; c++) STG(0, 1, c, 0);
#pragma unroll
    for (int c = 0; c < 4; c++) STG(57344, 0, c, 1);
#pragma unroll
    for (int c = 0; c < 3; c++) STG(57344, 1, c, 1);
    VMW(7);            // own tile0 chunks landed (tile1's 7 stay in flight)
    BARX();            // -> ALL waves' tile0 chunks landed
    LDA(0, smem); LDB(0, smem);     // pre-read group 0 ph0 operands (buf0)

    for (int g = 0; g < NT; ++g) {
        const int bo = (g & 1) * 57344;
        const char* cb = smem + bo;
        const char* nb = smem + (bo ^ 57344);
        // ---- ph0: MM(0,0) on pre-read a[0],b[0]; fetch A(qm1) for ph1 ----
        LDA(1, cb);
        MM(0, 0);
        BARX();
        // ---- ph1: MM(1,0); fetch B(qn1) for ph2 ----
        LDB(1, cb);
        MM(1, 0);
        BARX();
        // ---- ph2: MM(1,1); stage A(g+2) (A of buf read-complete since ph1-end); drain g+1 ----
        if (g + 2 < NT) { STG(bo, 0, 0, g + 2); STG(bo, 0, 1, g + 2);
                          STG(bo, 0, 2, g + 2); STG(bo, 0, 3, g + 2); }
        MM(1, 1);
        if (g + 2 < NT) { VMW(4); } else { VMW(0); }   // tile g+1 fully published after BAR
        BARX();
        // ---- ph3: pre-read B(qn0,g+1) (b[0] dead); stage B(g+2); MM(0,1); pre-read A(qm0,g+1) ----
        if (g + 1 < NT) LDB(0, nb);
        if (g + 2 < NT) { STG(bo, 1, 0, g + 2); STG(bo, 1, 1, g + 2); STG(bo, 1, 2, g + 2); }
        MM(0, 1);
        if (g + 1 < NT) LDA(0, nb);    // a[0] consumed by MM(0,1) above
        BARX();
    }

    if constexpr (BF16OUT) {
        bf16* lt = (bf16*)smem;                     // all LDS traffic done (final barrier above)
#pragma unroll
        for (int mf = 0; mf < 4; mf++) {
            const int row = wm * 64 + mf * 16 + quad * 4;
#pragma unroll
            for (int nf = 0; nf < 6; nf++) {
                const int col = wn * 96 + nf * 16 + l16;
                float bv = BIAS ? bias[bn + col] : 0.f;
#pragma unroll
                for (int r = 0; r < 4; r++) {
                    float v = acc[mf][nf][r] + bv;
                    if constexpr (RELU) v = fmaxf(v, 0.f);
                    lt[(row + r) * 200 + col] = f2b(v);
                }
            }
        }
        __syncthreads();
        bf16* C = (bf16*)Cv;
#pragma unroll
        for (int it = 0; it < 12; it++) {
            int c = it * 512 + tid;                 // 256 rows x 24 chunks of 8
            int rr = c / 24, cc = (c - rr * 24) * 8;
            *(short8*)(C + (size_t)(bm + rr) * N + bn + cc) =
                *(const short8*)(lt + rr * 200 + cc);
        }
    } else {
        float* C = (float*)Cv;
#pragma unroll
        for (int mf = 0; mf < 4; mf++) {
            const int gr = bm + wm * 64 + mf * 16 + quad * 4;
#pragma unroll
            for (int nf = 0; nf < 6; nf++) {
                const int gc = bn + wn * 96 + nf * 16 + l16;
                float bv = BIAS ? bias[gc] : 0.f;
#pragma unroll
                for (int r = 0; r < 4; r++) {
                    float v = acc[mf][nf][r] + bv;
                    if constexpr (RES) v += res[(size_t)(gr + r) * N + gc];
                    if constexpr (RELU) v = fmaxf(v, 0.f);
                    C[(size_t)(gr + r) * N + gc] = v;
                }
            }
        }
    }
#undef STG
#undef BARX
#undef VMW
#undef LDA
#undef LDB
#undef MM
}

// ---------------- causal attention, online softmax; qkv layout [BT][216]: q|k|v each 72 cols ----------------
__global__ __launch_bounds__(256) void attn_kernel(const bf16* __restrict__ qkv, bf16* __restrict__ o_pad)
{
    int blk = blockIdx.x;
    int half = blk & 1;
    int bh = blk >> 1;
    int b = bh / NH, h = bh % NH;
    int wave = threadIdx.x >> 6, lane = threadIdx.x & 63;
    const int jmap0[4] = {0, 2, 5, 7}, jmap1[4] = {1, 3, 4, 6};
    int j = half ? jmap1[wave] : jmap0[wave];
    int t = j * 64 + lane;
    int smax = half ? 448 : 512;

    __shared__ float ks[512 * 6];
    __shared__ float vs[512 * 6];
    const bf16* base = qkv + (size_t)b * 512 * 216;
    for (int i = threadIdx.x; i < smax * 6; i += 256) {
        int s = i / 6, e = i % 6;
        ks[i] = b2f(base[s * 216 + 72 + h * 6 + e]);
        vs[i] = b2f(base[s * 216 + 144 + h * 6 + e]);
    }
    __syncthreads();

    float q0 = b2f(base[t * 216 + h * 6 + 0]);
    float q1 = b2f(base[t * 216 + h * 6 + 1]);
    float q2 = b2f(base[t * 216 + h * 6 + 2]);
    float q3 = b2f(base[t * 216 + h * 6 + 3]);
    float q4 = b2f(base[t * 216 + h * 6 + 4]);
    float q5 = b2f(base[t * 216 + h * 6 + 5]);

    const float scale = 0.4082482904638630f;  // 1/sqrt(6)
    float m = -1e30f, l = 0.f;
    float o0 = 0, o1 = 0, o2 = 0, o3 = 0, o4 = 0, o5 = 0;
    for (int s = 0; s <= t; s++) {
        const float* kk = &ks[s * 6];
        float sc = (q0 * kk[0] + q1 * kk[1] + q2 * kk[2] + q3 * kk[3] + q4 * kk[4] + q5 * kk[5]) * scale;
        float nm = fmaxf(m, sc);
        float alpha = __expf(m - nm);
        float p = __expf(sc - nm);
        l = l * alpha + p;
        const float* vv = &vs[s * 6];
        o0 = o0 * alpha + p * vv[0];
        o1 = o1 * alpha + p * vv[1];
        o2 = o2 * alpha + p * vv[2];
        o3 = o3 * alpha + p * vv[3];
        o4 = o4 * alpha + p * vv[4];
        o5 = o5 * alpha + p * vv[5];
        m = nm;
    }
    float inv = 1.f / l;
    bf16* orow = o_pad + (size_t)(b * 512 + t) * 96 + h * 6;
    orow[0] = f2b(o0 * inv);
    orow[1] = f2b(o1 * inv);
    orow[2] = f2b(o2 * inv);
    orow[3] = f2b(o3 * inv);
    orow[4] = f2b(o4 * inv);
    orow[5] = f2b(o5 * inv);
    // cols 72..95 of o_pad stay poison (finite bf16): matching wo_t k-cols are zero -> contributes 0.
}

extern "C" void kernel_launch(void* const* d_in, const int* in_sizes, int n_in,
                              void* d_out, int out_size, void* d_ws, size_t ws_size,
                              hipStream_t stream)
{
    const float* x   = (const float*)d_in[0];
    const float* Wq  = (const float*)d_in[1];
    const float* Wk  = (const float*)d_in[2];
    const float* Wv  = (const float*)d_in[3];
    const float* Wo  = (const float*)d_in[4];
    const float* bo  = (const float*)d_in[5];
    const float* W1  = (const float*)d_in[6];
    const float* b1  = (const float*)d_in[7];
    const float* W2  = (const float*)d_in[8];
    const float* b2  = (const float*)d_in[9];
    const float* g1  = (const float*)d_in[10];
    const float* be1 = (const float*)d_in[11];
    const float* g2  = (const float*)d_in[12];
    const float* be2 = (const float*)d_in[13];

    char* ws = (char*)d_ws;
    size_t off = 0;
    auto alloc = [&](size_t bytes) {
        void* p = ws + off;
        off = (off + bytes + 255) & ~(size_t)255;
        return p;
    };
    bf16*  xn    = (bf16*)alloc((size_t)BT * DIM * 2);   // LN output (reused for both LNs)
    bf16*  qkvb  = (bf16*)alloc((size_t)BT * 216 * 2);
    bf16*  o_pad = (bf16*)alloc((size_t)BT * 96 * 2);
    float* x1    = (float*)alloc((size_t)BT * DIM * 4);  // residual stream after attention, fp32
    bf16*  ffb   = (bf16*)alloc((size_t)BT * DFF * 2);
    bf16*  wqkv  = (bf16*)alloc((size_t)256 * 768 * 2);  // padded to 256 rows (zeros)
    bf16*  wo_t  = (bf16*)alloc((size_t)768 * 96 * 2);
    bf16*  w1t   = (bf16*)alloc((size_t)3072 * 768 * 2);
    bf16*  w2t   = (bf16*)alloc((size_t)768 * 3072 * 2);

    // allow >64KB dynamic LDS on the 256x192 kernels (host-side, graph-capture safe)
    hipFuncSetAttribute(reinterpret_cast<const void*>(&gemm192_kernel<true, true, false, true>),
                        hipFuncAttributeMaxDynamicSharedMemorySize, 114688);
    hipFuncSetAttribute(reinterpret_cast<const void*>(&gemm192_kernel<false, true, true, false>),
                        hipFuncAttributeMaxDynamicSharedMemorySize, 114688);

    const int PACK_N = 256 * 768 + 768 * 96;
    pack_small_kernel<<<(PACK_N + 255) / 256, 256, 0, stream>>>(Wq, Wk, Wv, Wo, wqkv, wo_t);
    transpose_kernel<<<dim3(3072 / 32, 768 / 32), 256, 0, stream>>>(W1, w1t, 768, 3072);
    transpose_kernel<<<dim3(768 / 32, 3072 / 32), 256, 0, stream>>>(W2, w2t, 3072, 768);

    ln_kernel<<<BT, 192, 0, stream>>>(x, g1, be1, xn);
    gemm_kernel<2, false, false, false, true><<<dim3(128, 2), 256, 0, stream>>>(
        xn, wqkv, nullptr, nullptr, qkvb, BT, 216, 768);
    attn_kernel<<<32 * NH * 2, 256, 0, stream>>>(qkvb, o_pad);
    gemm_kernel<1, false, true, true, false><<<dim3(128, 6), 256, 0, stream>>>(
        o_pad, wo_t, bo, x, x1, BT, 768, 96);
    ln_kernel<<<BT, 192, 0, stream>>>(x1, g2, be2, xn);
    // FF1: [16384x768] @ [768x3072] -> bf16 (+bias, relu): grid 64x16 = 1024 (4 full rounds)
    gemm192_kernel<true, true, false, true><<<1024, 512, 114688, stream>>>(
        xn, w1t, b1, nullptr, ffb, BT, 3072, 768);
    // FF2: [16384x3072] @ [3072x768] -> fp32 (+bias, +res): grid 64x4 = 256 (full machine)
    gemm192_kernel<false, true, true, false><<<256, 512, 114688, stream>>>(
        ffb, w2t, b2, x1, (float*)d_out, BT, 768, 3072);
}